// Round 8
// baseline (7282.187 us; speedup 1.0000x reference)
//
#include <hip/hip_runtime.h>
#include <hip/hip_bf16.h>

#define DH 64
#define DM 256

typedef float f32x2 __attribute__((ext_vector_type(2)));

__device__ __forceinline__ f32x2 sp2(float s) { return (f32x2){s, s}; }
__device__ __forceinline__ f32x2 pkfma(f32x2 a, f32x2 b, f32x2 c) {
#if __has_builtin(__builtin_elementwise_fma)
    return __builtin_elementwise_fma(a, b, c);
#else
    f32x2 r; r.x = fmaf(a.x, b.x, c.x); r.y = fmaf(a.y, b.y, c.y); return r;
#endif
}

__device__ __forceinline__ float tanh_fast(float y) {
    float e = __expf(2.0f * y);
    return 1.0f - 2.0f / (e + 1.0f);
}
__device__ __forceinline__ float sigmoid_fast(float x) {
    return 1.0f / (1.0f + __expf(-x));
}

// DPP butterfly sum over 64 lanes; total lands in lane 63.
template <int CTRL, int RMASK>
__device__ __forceinline__ float dpp_term(float x) {
    int p = __builtin_amdgcn_update_dpp(0, __float_as_int(x), CTRL, RMASK, 0xf, false);
    return __int_as_float(p);
}
__device__ __forceinline__ float wave_sum63(float x) {
    x += dpp_term<0xB1,  0xf>(x);
    x += dpp_term<0x4E,  0xf>(x);
    x += dpp_term<0x141, 0xf>(x);
    x += dpp_term<0x140, 0xf>(x);
    x += dpp_term<0x142, 0xa>(x);
    x += dpp_term<0x143, 0xc>(x);
    return x;
}

// ---------------------------------------------------------------------------
// Kernel A: u[t][0..63] = phi[t]·thetaQ[h], u[t][64..127] = phi[t]·thetaK[h]
// ---------------------------------------------------------------------------
__global__ __launch_bounds__(256) void proj_kernel(
    const float* __restrict__ phi,
    const float* __restrict__ thK,
    const float* __restrict__ thQ,
    float* __restrict__ u,
    int dphi)
{
    const int tid  = threadIdx.x;
    const int th32 = tid & 31;
    const int tt8  = tid >> 5;
    const int t0   = tt8 * 4;
    const int h0   = th32 * 4;
    const int T0   = blockIdx.x * 32;

    __shared__ float sPhiT[32][36];
    __shared__ float sThT[32][128];

    const int h   = tid >> 1;
    const int ko  = (tid & 1) * 16;
    const float* trow = (h < 64) ? (thQ + (size_t)h * dphi)
                                 : (thK + (size_t)(h - 64) * dphi);
    const int tr  = tid >> 3;
    const int k4p = (tid & 7) * 4;

    float4 pv, tv0, tv1, tv2, tv3;
    pv  = *(const float4*)&phi[(size_t)(T0 + tr) * dphi + k4p];
    tv0 = *(const float4*)&trow[ko + 0];
    tv1 = *(const float4*)&trow[ko + 4];
    tv2 = *(const float4*)&trow[ko + 8];
    tv3 = *(const float4*)&trow[ko + 12];

    float acc[4][4];
    #pragma unroll
    for (int i = 0; i < 4; ++i)
        #pragma unroll
        for (int jj = 0; jj < 4; ++jj) acc[i][jj] = 0.0f;

    const int NC = dphi / 32;
    for (int c = 0; c < NC; ++c) {
        __syncthreads();
        sPhiT[k4p + 0][tr] = pv.x;
        sPhiT[k4p + 1][tr] = pv.y;
        sPhiT[k4p + 2][tr] = pv.z;
        sPhiT[k4p + 3][tr] = pv.w;
        sThT[ko +  0][h] = tv0.x;  sThT[ko +  1][h] = tv0.y;
        sThT[ko +  2][h] = tv0.z;  sThT[ko +  3][h] = tv0.w;
        sThT[ko +  4][h] = tv1.x;  sThT[ko +  5][h] = tv1.y;
        sThT[ko +  6][h] = tv1.z;  sThT[ko +  7][h] = tv1.w;
        sThT[ko +  8][h] = tv2.x;  sThT[ko +  9][h] = tv2.y;
        sThT[ko + 10][h] = tv2.z;  sThT[ko + 11][h] = tv2.w;
        sThT[ko + 12][h] = tv3.x;  sThT[ko + 13][h] = tv3.y;
        sThT[ko + 14][h] = tv3.z;  sThT[ko + 15][h] = tv3.w;
        __syncthreads();
        if (c + 1 < NC) {
            const int kb = (c + 1) * 32;
            pv  = *(const float4*)&phi[(size_t)(T0 + tr) * dphi + kb + k4p];
            tv0 = *(const float4*)&trow[kb + ko + 0];
            tv1 = *(const float4*)&trow[kb + ko + 4];
            tv2 = *(const float4*)&trow[kb + ko + 8];
            tv3 = *(const float4*)&trow[kb + ko + 12];
        }
        #pragma unroll 8
        for (int k = 0; k < 32; ++k) {
            float4 ph = *(const float4*)&sPhiT[k][t0];
            float4 th = *(const float4*)&sThT[k][h0];
            acc[0][0] = fmaf(ph.x, th.x, acc[0][0]);
            acc[0][1] = fmaf(ph.x, th.y, acc[0][1]);
            acc[0][2] = fmaf(ph.x, th.z, acc[0][2]);
            acc[0][3] = fmaf(ph.x, th.w, acc[0][3]);
            acc[1][0] = fmaf(ph.y, th.x, acc[1][0]);
            acc[1][1] = fmaf(ph.y, th.y, acc[1][1]);
            acc[1][2] = fmaf(ph.y, th.z, acc[1][2]);
            acc[1][3] = fmaf(ph.y, th.w, acc[1][3]);
            acc[2][0] = fmaf(ph.z, th.x, acc[2][0]);
            acc[2][1] = fmaf(ph.z, th.y, acc[2][1]);
            acc[2][2] = fmaf(ph.z, th.z, acc[2][2]);
            acc[2][3] = fmaf(ph.z, th.w, acc[2][3]);
            acc[3][0] = fmaf(ph.w, th.x, acc[3][0]);
            acc[3][1] = fmaf(ph.w, th.y, acc[3][1]);
            acc[3][2] = fmaf(ph.w, th.z, acc[3][2]);
            acc[3][3] = fmaf(ph.w, th.w, acc[3][3]);
        }
    }
    #pragma unroll
    for (int i = 0; i < 4; ++i) {
        float4 o;
        o.x = acc[i][0]; o.y = acc[i][1]; o.z = acc[i][2]; o.w = acc[i][3];
        *(float4*)&u[(size_t)(T0 + t0 + i) * 128 + h0] = o;
    }
}

// ---------------------------------------------------------------------------
// Kernel A2: dd4[t] = { uk(t-1)·uq(t), uk(t-1)·uk(t),
//                       uk(t-2)·uq(t), uk(t-2)·uk(t) }   (zeros at edges)
// ---------------------------------------------------------------------------
__global__ __launch_bounds__(256) void dots_kernel(
    const float* __restrict__ u, float4* __restrict__ dd4, int T)
{
    const int t    = (blockIdx.x * 256 + threadIdx.x) >> 6;
    const int lane = threadIdx.x & 63;
    if (t >= T) return;
    float uq = u[(size_t)t * 128 + lane];
    float uk = u[(size_t)t * 128 + 64 + lane];
    float k1 = (t >= 1) ? u[(size_t)(t - 1) * 128 + 64 + lane] : 0.f;
    float k2 = (t >= 2) ? u[(size_t)(t - 2) * 128 + 64 + lane] : 0.f;
    float a = k1 * uq, b = k1 * uk, c = k2 * uq, d = k2 * uk;
    #pragma unroll
    for (int off = 32; off > 0; off >>= 1) {
        a += __shfl_xor(a, off);
        b += __shfl_xor(b, off);
        c += __shfl_xor(c, off);
        d += __shfl_xor(d, off);
    }
    if (lane == 0) dd4[t] = make_float4(a, b, c, d);
}

// ---------------------------------------------------------------------------
// Kernel B: sequential TTT scan — ONE barrier/step, depth-2 deferral,
// wave-uniform operands (u slices, dots, C) read from GLOBAL into register
// ping-pong buffers one step ahead (scalar/VMEM pipes; DS pipe only carries
// the cross-thread exchanges: pbuf / ebufT / pqk, ~21 KB total).
// ---------------------------------------------------------------------------

#define ROWU(uqs, uks, ums, i2) do {                                         \
    f32x2 wa_ = pkfma(sp2(-(ums)), e1g0_, w1p[i2]);                          \
    f32x2 wb_ = pkfma(sp2(-(ums)), e1g1_, w1p[(i2) + 1]);                    \
    w1p[i2] = wa_; w1p[(i2) + 1] = wb_;                                      \
    aq0_ = pkfma(sp2(uqs), wa_, aq0_);  aq1_ = pkfma(sp2(uqs), wb_, aq1_);   \
    ak0_ = pkfma(sp2(uks), wa_, ak0_);  ak1_ = pkfma(sp2(uks), wb_, ak1_);   \
} while (0)
#define ROWU4(q4, k4, m4, b) do {                                            \
    ROWU((q4).x, (k4).x, (m4).x, (b) + 0);                                   \
    ROWU((q4).y, (k4).y, (m4).y, (b) + 2);                                   \
    ROWU((q4).z, (k4).z, (m4).z, (b) + 4);                                   \
    ROWU((q4).w, (k4).w, (m4).w, (b) + 6);                                   \
} while (0)
#define ROWM(uqs, uks, i2) do {                                              \
    aq0_ = pkfma(sp2(uqs), w1p[i2], aq0_);                                   \
    aq1_ = pkfma(sp2(uqs), w1p[(i2) + 1], aq1_);                             \
    ak0_ = pkfma(sp2(uks), w1p[i2], ak0_);                                   \
    ak1_ = pkfma(sp2(uks), w1p[(i2) + 1], ak1_);                             \
} while (0)
#define ROWM4(q4, k4, b) do {                                                \
    ROWM((q4).x, (k4).x, (b) + 0);                                           \
    ROWM((q4).y, (k4).y, (b) + 2);                                           \
    ROWM((q4).z, (k4).z, (b) + 4);                                           \
    ROWM((q4).w, (k4).w, (b) + 6);                                           \
} while (0)

#define STEP(t_, QC, QN, KC, KN, MC, MN, DDC, DDN, CC, CN) do {              \
    const int pbR_ = (t_) & 1;                                               \
    /* prefetch next-step uniform operands from GLOBAL (off DS pipe) */      \
    {                                                                        \
        const int tn_ = ((t_) + 2 < T) ? (t_) + 2 : T - 1;                   \
        const float4* upn_ = (const float4*)(u + (size_t)tn_ * 128);         \
        QN[0] = upn_[uq4 + 0]; QN[1] = upn_[uq4 + 1];                        \
        QN[2] = upn_[uq4 + 2]; QN[3] = upn_[uq4 + 3];                        \
        KN[0] = upn_[uk4 + 0]; KN[1] = upn_[uk4 + 1];                        \
        KN[2] = upn_[uk4 + 2]; KN[3] = upn_[uk4 + 3];                        \
        const int tm_ = ((t_) >= 1) ? (t_) - 1 : 0;                          \
        const float4* upm_ = (const float4*)(u + (size_t)tm_ * 128);         \
        MN[0] = upm_[uk4 + 0]; MN[1] = upm_[uk4 + 1];                        \
        MN[2] = upm_[uk4 + 2]; MN[3] = upm_[uk4 + 3];                        \
        const int td_ = ((t_) + 1 < T) ? (t_) + 1 : T - 1;                   \
        DDN = dd_g4[td_];                                                    \
        CN  = C_seq[t_];                                                     \
    }                                                                        \
    /* LDS reads (issued early) */                                           \
    float4 pqQ_ = *(const float4*)&pqk[pbR_ ^ 1][0];                         \
    float4 pqK_ = *(const float4*)&pqk[pbR_ ^ 1][4];                         \
    const int sE_ = ((t_) + 2) & 3;                                          \
    float eb0_ = ebufT[sE_][0][lane];                                        \
    float eb1_ = ebufT[sE_][1][lane];                                        \
    float eb2_ = ebufT[sE_][2][lane];                                        \
    float eb3_ = ebufT[sE_][3][lane];                                        \
    float pA0_ = pbuf[pbR_][0][0][j], pA1_ = pbuf[pbR_][1][0][j];            \
    float pA2_ = pbuf[pbR_][2][0][j], pA3_ = pbuf[pbR_][3][0][j];            \
    float pB0_ = pbuf[pbR_][0][1][j], pB1_ = pbuf[pbR_][1][1][j];            \
    float pB2_ = pbuf[pbR_][2][1][j], pB3_ = pbuf[pbR_][3][1][j];            \
    /* chain head: finish step t-1 */                                        \
    float zs_ = ((pqQ_.x + pqQ_.y) + (pqQ_.z + pqQ_.w)) + b2;                \
    float zp_ = ((pqK_.x + pqK_.y) + (pqK_.z + pqK_.w)) + b2;                \
    float s_    = sigmoid_fast(zs_);                                         \
    float pred_ = sigmoid_fast(zp_);                                         \
    float dZ2_  = 2.f * pred_ * pred_ * (1.f - pred_);                       \
    /* off-chain: UPD (e1(t-2), via dZ2p) fused with MV(t+1) */              \
    f32x2 e1g0_ = sp2(dZ2p) * (f32x2){eb0_, eb1_};                           \
    f32x2 e1g1_ = sp2(dZ2p) * (f32x2){eb2_, eb3_};                           \
    f32x2 aq0_ = sp2(0.f), aq1_ = sp2(0.f), ak0_ = sp2(0.f), ak1_ = sp2(0.f);\
    ROWU4(QC[0], KC[0], MC[0], 0);                                           \
    ROWU4(QC[1], KC[1], MC[1], 8);                                           \
    ROWU4(QC[2], KC[2], MC[2], 16);                                          \
    ROWU4(QC[3], KC[3], MC[3], 24);                                          \
    { float4 wq_; wq_.x = aq0_.x; wq_.y = aq0_.y; wq_.z = aq1_.x; wq_.w = aq1_.y; \
      *(float4*)&pbuf[pbR_ ^ 1][wv][0][lane * 4] = wq_;                      \
      float4 wk_; wk_.x = ak0_.x; wk_.y = ak0_.y; wk_.z = ak1_.x; wk_.w = ak1_.y; \
      *(float4*)&pbuf[pbR_ ^ 1][wv][1][lane * 4] = wk_; }                    \
    /* scalar state + z(t) */                                                \
    float e1o_  = dZ2_ * en1;                                                \
    float e1o2_ = dZ2p * en2;                                                \
    b1j -= e1o_;                                                             \
    w2j  = fmaf(-eta * dZ2_, x2p, w2j);                                      \
    b2  -= eta * dZ2_;                                                       \
    float Pq_ = ((pA0_ + pA1_) + (pA2_ + pA3_));                             \
    float Pk_ = ((pB0_ + pB1_) + (pB2_ + pB3_));                             \
    float zq_ = Pq_ + b1j - e1o2_ * DDC.z - e1o_ * DDC.x;                    \
    float zk_ = Pk_ + b1j - e1o2_ * DDC.w - e1o_ * DDC.y;                    \
    float tk_ = tanh_fast(0.79788456f * zk_ * fmaf(0.044715f, zk_*zk_, 1.f));\
    float x2_ = 0.5f * zk_ * (1.f + tk_);                                    \
    float tq_ = tanh_fast(0.79788456f * zq_ * fmaf(0.044715f, zq_*zq_, 1.f));\
    float aq_ = 0.5f * zq_ * (1.f + tq_);                                    \
    float gb_ = 0.5f * zk_ * ((1.f - tk_*tk_) *                              \
                fmaf(0.1070322243f, zk_*zk_, 0.79788456f))                   \
              + 0.5f * (1.f + tk_);                                          \
    float en_ = eta * w2j * gb_;                                             \
    ebufT[(t_) & 3][j & 3][j >> 2] = en_;                                    \
    float pqs_ = wave_sum63(aq_ * w2j);                                      \
    float pks_ = wave_sum63(x2_ * w2j);                                      \
    if (lane == 63) { pqk[(t_) & 1][wv] = pqs_; pqk[(t_) & 1][4 + wv] = pks_; } \
    if ((t_) > 0) {                                                          \
        if (j == 0) out[(t_) - 1] = s_;                                      \
        float df_ = s_ - CC;                                                 \
        loss = fmaf(df_, df_, loss);                                         \
    }                                                                        \
    dZ2p = dZ2_; en2 = en1; en1 = en_; x2p = x2_;                            \
    asm volatile("s_waitcnt lgkmcnt(0)" ::: "memory");                       \
    __builtin_amdgcn_s_barrier();                                            \
    asm volatile("" ::: "memory");                                           \
} while (0)

__global__ __launch_bounds__(256, 1) void ttt_scan(
    const float* __restrict__ u,       // [T][128]
    const float4* __restrict__ dd_g4,  // [T] lag-1/lag-2 dots
    const float* __restrict__ C_seq,   // [T]
    const float* __restrict__ W10,     // [64][256]
    const float* __restrict__ b10,     // [256]
    const float* __restrict__ W20,     // [256]
    const float* __restrict__ b20,     // [1]
    const float* __restrict__ log_eta, // [1]
    float* __restrict__ out,           // [T+1]
    int T)
{
    const int j    = threadIdx.x;
    const int lane = j & 63;
    const int wv   = j >> 6;
    const int uq4  = 4 * wv;           // float4 index of q slice
    const int uk4  = 16 + 4 * wv;      // float4 index of k slice

    __shared__ __align__(16) float pbuf[2][4][2][256];   // 16 KB
    __shared__ __align__(16) float ebufT[4][4][72];      // 4.6 KB
    __shared__ __align__(16) float pqk[2][8];

    // ---- prologue init ----
    if (j < 8)  pqk[1][j] = -2.5e29f;          // step "-1": pred = 0, dZ2 = 0
    {
        float* ez = &ebufT[2][0][0];           // zero slots 2,3
        for (int k = j; k < 2 * 4 * 72; k += 256) ez[k] = 0.f;
    }

    // wave wv owns W1 rows [16wv,16wv+16); lane owns cols [4*lane,4*lane+4)
    f32x2 w1p[32];
    #pragma unroll
    for (int i = 0; i < 16; ++i) {
        float4 wr = *(const float4*)&W10[(16 * wv + i) * DM + lane * 4];
        w1p[2 * i]     = (f32x2){wr.x, wr.y};
        w1p[2 * i + 1] = (f32x2){wr.z, wr.w};
    }
    float b1j = b10[j];
    float w2j = W20[j];
    float b2  = b20[0];
    const float eta = __expf(log_eta[0]);
    float loss = 0.0f;
    float dZ2p = 0.0f, en1 = 0.0f, en2 = 0.0f, x2p = 0.0f;

    // register ping-pong buffers for uniform operands
    float4 qA[4], qB[4], kA[4], kB[4], mA[4], mB[4];
    float4 ddA, ddB;
    float  cA, cB;

    // peel: pbuf(0) = u(0)·W1(0); also init A-set buffers
    {
        const float4* up0 = (const float4*)u;
        float4 q40 = up0[uq4 + 0], q41 = up0[uq4 + 1];
        float4 q42 = up0[uq4 + 2], q43 = up0[uq4 + 3];
        float4 k40 = up0[uk4 + 0], k41 = up0[uk4 + 1];
        float4 k42 = up0[uk4 + 2], k43 = up0[uk4 + 3];
        f32x2 aq0_ = sp2(0.f), aq1_ = sp2(0.f), ak0_ = sp2(0.f), ak1_ = sp2(0.f);
        ROWM4(q40, k40, 0);
        ROWM4(q41, k41, 8);
        ROWM4(q42, k42, 16);
        ROWM4(q43, k43, 24);
        float4 wq; wq.x = aq0_.x; wq.y = aq0_.y; wq.z = aq1_.x; wq.w = aq1_.y;
        *(float4*)&pbuf[0][wv][0][lane * 4] = wq;
        float4 wk; wk.x = ak0_.x; wk.y = ak0_.y; wk.z = ak1_.x; wk.w = ak1_.y;
        *(float4*)&pbuf[0][wv][1][lane * 4] = wk;

        // A-set: u(1) slices, m = 0 (finite; multiplied by dZ2p = 0)
        const int t1 = (T > 1) ? 1 : 0;
        const float4* up1 = (const float4*)(u + (size_t)t1 * 128);
        #pragma unroll
        for (int i = 0; i < 4; ++i) {
            qA[i] = up1[uq4 + i];
            kA[i] = up1[uk4 + i];
            mA[i] = make_float4(0.f, 0.f, 0.f, 0.f);
        }
        ddA = dd_g4[0];
        cA  = C_seq[0];
    }
    __syncthreads();

    for (int t = 0; t < T; t += 2) {
        STEP(t,     qA, qB, kA, kB, mA, mB, ddA, ddB, cA, cB);
        STEP(t + 1, qB, qA, kB, kA, mB, mA, ddB, ddA, cB, cA);
    }

    // final: finish step T-1
    {
        float4 pqQ = *(const float4*)&pqk[(T - 1) & 1][0];
        float zs = ((pqQ.x + pqQ.y) + (pqQ.z + pqQ.w)) + b2;
        float s_ = sigmoid_fast(zs);
        float cv = C_seq[T - 1];
        float df = s_ - cv;
        loss = fmaf(df, df, loss);
        if (j == 0) { out[T - 1] = s_; out[T] = loss; }
    }
}

// ---------------------------------------------------------------------------
extern "C" void kernel_launch(void* const* d_in, const int* in_sizes, int n_in,
                              void* d_out, int out_size, void* d_ws, size_t ws_size,
                              hipStream_t stream) {
    const float* phi     = (const float*)d_in[0];
    const float* C_seq   = (const float*)d_in[1];
    const float* thK     = (const float*)d_in[2];
    const float* thQ     = (const float*)d_in[3];
    const float* W10     = (const float*)d_in[4];
    const float* b10     = (const float*)d_in[5];
    const float* W20     = (const float*)d_in[6];
    const float* b20     = (const float*)d_in[7];
    const float* log_eta = (const float*)d_in[8];

    const int T    = in_sizes[1];          // 8192
    const int dphi = in_sizes[0] / T;      // 4096

    float*  uw  = (float*)d_ws;                                             // [T][128]
    float4* dd4 = (float4*)((char*)d_ws + (size_t)T * 128 * sizeof(float)); // [T]

    proj_kernel<<<T / 32, 256, 0, stream>>>(phi, thK, thQ, uw, dphi);
    dots_kernel<<<T / 4, 256, 0, stream>>>(uw, dd4, T);
    ttt_scan<<<1, 256, 0, stream>>>(uw, dd4, C_seq, W10, b10, W20, b20, log_eta,
                                    (float*)d_out, T);
}